// Round 1
// baseline (981.400 us; speedup 1.0000x reference)
//
#include <hip/hip_runtime.h>
#include <stdint.h>

// Problem constants
#define B_ 8
#define C_ 256
#define L_ 2048
#define K_ 8192
#define M_ 16384   // B_*L_

// GEMM tiling
#define TILE_M 128
#define TILE_N 256
#define KCH 32
#define NSPLIT 4
#define CODES_PER_SPLIT (K_ / NSPLIT)      // 2048
#define NTILES (CODES_PER_SPLIT / TILE_N)  // 8

// ---- workspace layout (bytes) ----
// [0, 131072)        : keys (u64[M_])
// [131072, 131076)   : loss accumulator (float)
// [131328, 196864)   : xsq (float[M_])
// [196864, 229632)   : csq (float[K_])
#define WS_KEYS   0
#define WS_LOSS   131072
#define WS_XSQ    131328
#define WS_CSQ    196864

__global__ void vq_xsq(const float* __restrict__ x, float* __restrict__ xsq) {
  int m = blockIdx.x * 256 + threadIdx.x;          // 64 blocks * 256
  int b = m >> 11, l = m & 2047;
  const float* p = x + (size_t)b * (C_ * L_) + l;
  float s = 0.0f;
#pragma unroll 8
  for (int c = 0; c < C_; ++c) {
    float v = p[(size_t)c * L_];
    s = __fadd_rn(s, __fmul_rn(v, v));
  }
  xsq[m] = s;
}

__global__ void vq_csq(const float* __restrict__ cb, float* __restrict__ csq) {
  int t = threadIdx.x;
  int k = blockIdx.x * 16 + (t >> 4);              // 512 blocks * 256 thr
  int g = t & 15;
  const float* row = cb + (size_t)k * C_;
  float s = 0.0f;
#pragma unroll
  for (int j = 0; j < 4; ++j) {
    float4 v = *(const float4*)&row[g * 4 + j * 64];
    s += v.x * v.x + v.y * v.y + v.z * v.z + v.w * v.w;
  }
#pragma unroll
  for (int off = 1; off < 16; off <<= 1) s += __shfl_xor(s, off, 64);
  if (g == 0) csq[k] = s;
}

// Main distance-GEMM + running argmax.
// Block: 256 threads, BM=128 rows x BN=256 codes per tile, 8 tiles per block.
// Thread (tr=tid&15, tc=tid>>4): rows {4tr+i, 4tr+64+i}, codes {tc+16*jc}.
__global__ void __launch_bounds__(256, 2)
vq_dist_argmax(const float* __restrict__ x, const float* __restrict__ cb,
               const float* __restrict__ xsq, const float* __restrict__ csq,
               unsigned long long* __restrict__ keys) {
  __shared__ float As[KCH * TILE_M];   // [c][m], 16 KB
  __shared__ float Bs[TILE_N * KCH];   // [k][quad-swizzled c], 32 KB

  const int tid = threadIdx.x;
  const int bid = blockIdx.x;
  const int mtile = bid & 127;
  const int split = bid >> 7;                 // 0..NSPLIT-1
  const int bb = mtile >> 4;                  // batch index (16 mtiles per b)
  const int l0 = (mtile & 15) * TILE_M;
  const int m0 = mtile * TILE_M;
  const int tr = tid & 15;
  const int tc = tid >> 4;

  // preload ||x||^2 for my 8 rows
  float xq[8];
#pragma unroll
  for (int jr = 0; jr < 2; ++jr)
#pragma unroll
    for (int i = 0; i < 4; ++i)
      xq[jr * 4 + i] = xsq[m0 + 4 * tr + 64 * jr + i];

  float bestv[8];
  int bestk[8];
#pragma unroll
  for (int r = 0; r < 8; ++r) { bestv[r] = -1.0f; bestk[r] = 0; }

  for (int nt = 0; nt < NTILES; ++nt) {
    const int k0 = split * CODES_PER_SPLIT + nt * TILE_N;

    float acc[16][8];
#pragma unroll
    for (int jc = 0; jc < 16; ++jc)
#pragma unroll
      for (int r = 0; r < 8; ++r) acc[jc][r] = 0.0f;

    for (int cc = 0; cc < C_ / KCH; ++cc) {   // 8 chunks of 32 channels
      const int c0 = cc * KCH;
      __syncthreads();  // protect LDS from previous chunk's readers
      // stage A: x[bb][c0+c][l0 .. l0+127] -> As[c][m]   (natural layout!)
#pragma unroll
      for (int j = 0; j < 4; ++j) {
        int idx = tid + 256 * j;              // 0..1023 float4s
        int c = idx >> 5;                     // 0..31
        int qm = idx & 31;                    // 0..31
        float4 v = *(const float4*)&x[(size_t)(bb * C_ + c0 + c) * L_ + l0 + 4 * qm];
        *(float4*)&As[c * TILE_M + 4 * qm] = v;
      }
      // stage B: cb[k0+k][c0 + 4*c4 .. +3] -> Bs[32k + 4*(c4^(k&7))] (swizzled)
#pragma unroll
      for (int it = 0; it < 8; ++it) {
        int k = (tid >> 3) + 32 * it;         // 0..255
        int c4 = tid & 7;
        float4 v = *(const float4*)&cb[(size_t)(k0 + k) * C_ + c0 + 4 * c4];
        *(float4*)&Bs[32 * k + 4 * (c4 ^ (k & 7))] = v;
      }
      __syncthreads();

#pragma unroll 2
      for (int c4 = 0; c4 < 8; ++c4) {
        float a_[4][8];  // [ci][r]
#pragma unroll
        for (int ci = 0; ci < 4; ++ci) {
          int c = 4 * c4 + ci;
          float4 t0 = *(const float4*)&As[c * TILE_M + 4 * tr];
          float4 t1 = *(const float4*)&As[c * TILE_M + 4 * tr + 64];
          a_[ci][0] = t0.x; a_[ci][1] = t0.y; a_[ci][2] = t0.z; a_[ci][3] = t0.w;
          a_[ci][4] = t1.x; a_[ci][5] = t1.y; a_[ci][6] = t1.z; a_[ci][7] = t1.w;
        }
#pragma unroll
        for (int jc = 0; jc < 16; ++jc) {
          int k = tc + 16 * jc;
          float4 bv = *(const float4*)&Bs[32 * k + 4 * (c4 ^ (k & 7))];
          float bs[4] = {bv.x, bv.y, bv.z, bv.w};
#pragma unroll
          for (int ci = 0; ci < 4; ++ci)
#pragma unroll
            for (int r = 0; r < 8; ++r)
              acc[jc][r] = fmaf(a_[ci][r], bs[ci], acc[jc][r]);
        }
      }
    }

    // epilogue: dist + running argmax (k ascending within thread -> first-max)
#pragma unroll
    for (int jc = 0; jc < 16; ++jc) {
      int kg = k0 + tc + 16 * jc;
      float cs = csq[kg];
#pragma unroll
      for (int r = 0; r < 8; ++r) {
        // mirror numpy: (x_sq + c_sq) - 2*dot, clamp, correctly-rounded sqrt
        float d2 = __fsub_rn(__fadd_rn(xq[r], cs), __fmul_rn(2.0f, acc[jc][r]));
        float dist = sqrtf(fmaxf(d2, 0.0f));
        if (dist > bestv[r]) { bestv[r] = dist; bestk[r] = kg; }
      }
    }
  }

  // merge: key = (dist_bits << 32) | (~k)  => max dist, ties -> smaller k
#pragma unroll
  for (int r = 0; r < 8; ++r) {
    int m = m0 + 4 * tr + 64 * (r >> 2) + (r & 3);
    unsigned long long key =
        ((unsigned long long)__float_as_uint(bestv[r]) << 32) |
        (unsigned long long)(0xFFFFFFFFu - (unsigned)bestk[r]);
    atomicMax(&keys[m], key);
  }
}

__global__ void vq_code(const unsigned long long* __restrict__ keys,
                        float* __restrict__ out) {
  int m = blockIdx.x * 256 + threadIdx.x;     // 64 blocks
  unsigned k = 0xFFFFFFFFu - (unsigned)(keys[m] & 0xFFFFFFFFull);
  out[m] = (float)k;
}

// emb gather + loss partial. Block: one (b, 32-l chunk). 512 blocks * 256 thr.
__global__ void __launch_bounds__(256)
vq_gather(const unsigned long long* __restrict__ keys,
          const float* __restrict__ cb, const float* __restrict__ x,
          float* __restrict__ emb, float* __restrict__ loss_acc) {
  __shared__ float rows[32 * 260];   // padded, 16B-aligned rows
  __shared__ int codes_s[32];
  __shared__ float partial[4];

  int t = threadIdx.x;
  int b = blockIdx.x >> 6;
  int l0 = (blockIdx.x & 63) * 32;

  if (t < 32) {
    unsigned long long key = keys[b * L_ + l0 + t];
    codes_s[t] = (int)(0xFFFFFFFFu - (unsigned)(key & 0xFFFFFFFFull));
  }
  __syncthreads();
  {
    int r = t >> 3, c4 = t & 7;
    const float* src = cb + (size_t)codes_s[r] * C_;
#pragma unroll
    for (int j = 0; j < 8; ++j) {
      float4 v = *(const float4*)&src[(c4 + 8 * j) * 4];
      *(float4*)&rows[r * 260 + (c4 + 8 * j) * 4] = v;
    }
  }
  __syncthreads();

  float ls = 0.0f;
  int l = t & 31, cg = t >> 5;
#pragma unroll 4
  for (int cs = 0; cs < 32; ++cs) {
    int c = cg * 32 + cs;
    float v = rows[l * 260 + c];
    size_t gi = (size_t)(b * C_ + c) * L_ + l0 + l;
    emb[gi] = v;
    float d = x[gi] - v;
    ls = fmaf(d, d, ls);
  }
#pragma unroll
  for (int off = 1; off < 64; off <<= 1) ls += __shfl_xor(ls, off, 64);
  if ((t & 63) == 0) partial[t >> 6] = ls;
  __syncthreads();
  if (t == 0)
    atomicAdd(loss_acc, partial[0] + partial[1] + partial[2] + partial[3]);
}

__global__ void vq_loss(const float* __restrict__ loss_acc,
                        float* __restrict__ out) {
  out[0] = loss_acc[0] / 4194304.0f;   // mean over B*C*L
}

extern "C" void kernel_launch(void* const* d_in, const int* in_sizes, int n_in,
                              void* d_out, int out_size, void* d_ws, size_t ws_size,
                              hipStream_t stream) {
  const float* x  = (const float*)d_in[0];   // (8, 256, 2048)
  const float* cb = (const float*)d_in[1];   // (8192, 256)
  float* out = (float*)d_out;                // [code(16384) | emb(4194304) | loss(1)]
  char* ws = (char*)d_ws;

  unsigned long long* keys = (unsigned long long*)(ws + WS_KEYS);
  float* loss_acc = (float*)(ws + WS_LOSS);
  float* xsq = (float*)(ws + WS_XSQ);
  float* csq = (float*)(ws + WS_CSQ);

  hipMemsetAsync(ws, 0, WS_LOSS + 8, stream);           // keys + loss accumulator
  vq_xsq<<<M_ / 256, 256, 0, stream>>>(x, xsq);
  vq_csq<<<K_ / 16, 256, 0, stream>>>(cb, csq);
  vq_dist_argmax<<<128 * NSPLIT, 256, 0, stream>>>(x, cb, xsq, csq, keys);
  vq_code<<<M_ / 256, 256, 0, stream>>>(keys, out);
  vq_gather<<<(B_ * L_) / 32, 256, 0, stream>>>(keys, cb, x, out + M_, loss_acc);
  vq_loss<<<1, 1, 0, stream>>>(loss_acc, out + M_ + B_ * C_ * L_);
}

// Round 2
// 517.889 us; speedup vs baseline: 1.8950x; 1.8950x over previous
//
#include <hip/hip_runtime.h>
#include <stdint.h>

typedef unsigned int u32;
typedef unsigned long long u64;
typedef unsigned short ushort_t;

// Problem constants
#define B_ 8
#define C_ 256
#define L_ 2048
#define K_ 8192
#define M_ 16384   // B_*L_

// ---- workspace layout (bytes) ----
#define WS_KEYS   0            // u64[16384] = 131072
#define WS_CNT    131072       // u32
#define WS_MAXCS  131076       // u32 (float bits, positive -> int cmp ok)
#define WS_LOSS   131080       // f32
// memset range [0, 131084)
#define WS_XSQ    131328       // f32[16384] -> 196864
#define WS_CSQ    196864       // f32[8192]  -> 229632
#define WS_THR    229632       // f32[16384] -> 295168
#define WS_LMAX   295168       // f32[16384*64] -> 4489472
#define WS_LIST   4489472      // u32[2M] -> 12878080
#define WS_XTH    12878080     // bf16[16384*256] -> 21266688
#define WS_CBH    21266688     // bf16[8192*256]  -> 25460992
#define WS_NEED   25460992
#define LIST_CAP  2097152u

typedef __attribute__((ext_vector_type(8))) short s8v;   // 8 x bf16 (4 VGPR)
typedef __attribute__((ext_vector_type(4))) float f4v;

__device__ __forceinline__ ushort_t f2bf(float f) {
  u32 u = __float_as_uint(f);
  u32 r = (u + 0x7FFFu + ((u >> 16) & 1u)) >> 16;   // RN-even
  return (ushort_t)r;
}

__device__ __forceinline__ void gld16(void* lds, const void* g) {
  __builtin_amdgcn_global_load_lds(
      (const __attribute__((address_space(1))) u32*)g,
      (__attribute__((address_space(3))) u32*)lds, 16, 0, 0);
}

// ---------------- aux kernels (shared by both paths) ----------------

__global__ void vq_xsq(const float* __restrict__ x, float* __restrict__ xsq) {
  int m = blockIdx.x * 256 + threadIdx.x;          // 64 blocks
  int b = m >> 11, l = m & 2047;
  const float* p = x + (size_t)b * (C_ * L_) + l;
  float s = 0.0f;
#pragma unroll 8
  for (int c = 0; c < C_; ++c) {
    float v = p[(size_t)c * L_];
    s = __fadd_rn(s, __fmul_rn(v, v));
  }
  xsq[m] = s;
}

__global__ void vq_csq(const float* __restrict__ cb, float* __restrict__ csq,
                       int* __restrict__ maxcs) {
  int t = threadIdx.x;
  int k = blockIdx.x * 16 + (t >> 4);              // 512 blocks
  int g = t & 15;
  const float* row = cb + (size_t)k * C_;
  float s = 0.0f;
#pragma unroll
  for (int j = 0; j < 4; ++j) {
    float4 v = *(const float4*)&row[g * 4 + j * 64];
    s += v.x * v.x + v.y * v.y + v.z * v.z + v.w * v.w;
  }
#pragma unroll
  for (int off = 1; off < 16; off <<= 1) s += __shfl_xor(s, off, 64);
  if (g == 0) {
    csq[k] = s;
    atomicMax(maxcs, __float_as_int(s));   // positive floats: int cmp == float cmp
  }
}

// transpose x (B,C,L) -> xt fp32 (M,C) [into emb out region] + bf16 (M,C) [ws]
__global__ void __launch_bounds__(256)
vq_transpose(const float* __restrict__ x, float* __restrict__ xtf,
             ushort_t* __restrict__ xth) {
  __shared__ float t[64][65];
  int tid = threadIdx.x;
  int b  = blockIdx.x >> 7;
  int cc = (blockIdx.x >> 5) & 3;
  int lc = blockIdx.x & 31;
#pragma unroll
  for (int j = 0; j < 4; ++j) {
    int c  = (tid >> 4) + j * 16;
    int lq = tid & 15;
    float4 v = *(const float4*)&x[((size_t)(b * C_ + cc * 64 + c)) * L_ + lc * 64 + lq * 4];
    t[c][lq * 4 + 0] = v.x; t[c][lq * 4 + 1] = v.y;
    t[c][lq * 4 + 2] = v.z; t[c][lq * 4 + 3] = v.w;
  }
  __syncthreads();
  int l = tid >> 2, qc = tid & 3;
  size_t m = (size_t)b * L_ + lc * 64 + l;
#pragma unroll
  for (int j = 0; j < 4; ++j) {
    int q = qc + j * 4;                    // float4 index 0..15
    float4 v = make_float4(t[q * 4 + 0][l], t[q * 4 + 1][l],
                           t[q * 4 + 2][l], t[q * 4 + 3][l]);
    *(float4*)&xtf[m * C_ + cc * 64 + q * 4] = v;
    ushort4 h;
    h.x = f2bf(v.x); h.y = f2bf(v.y); h.z = f2bf(v.z); h.w = f2bf(v.w);
    *(ushort4*)&xth[m * C_ + cc * 64 + q * 4] = h;
  }
}

__global__ void vq_cbconv(const float* __restrict__ cb, ushort_t* __restrict__ cbh) {
  int i = blockIdx.x * 256 + threadIdx.x;   // 2048 blocks, float4 each
  float4 v = *(const float4*)&cb[(size_t)i * 4];
  ushort4 h;
  h.x = f2bf(v.x); h.y = f2bf(v.y); h.z = f2bf(v.z); h.w = f2bf(v.w);
  *(ushort4*)&cbh[(size_t)i * 4] = h;
}

// ---------------- MFMA distance GEMM (two phases) ----------------
// BM=BN=128, BK=64, 256 threads (4 waves, 2x2), wave tile 64x64.
// PHASE 1: write per-(row, nblock) approx-d2 max.
// PHASE 2: append (row,code) with d2 >= thr[row] to candidate list.
template<int PHASE>
__global__ void __launch_bounds__(256, 3)
vq_mfma_pass(const ushort_t* __restrict__ xt, const ushort_t* __restrict__ cbh,
             const float* __restrict__ xsq, const float* __restrict__ csq,
             float* __restrict__ lmax, const float* __restrict__ thr,
             u32* __restrict__ list, u32* __restrict__ cnt) {
  __shared__ short As[128 * 64];   // [row][k] bf16, 16KB
  __shared__ short Bs[128 * 64];
  __shared__ float red[128][2];
  __shared__ float thr_s[128];

  const int tid = threadIdx.x;
  const int w = tid >> 6, l = tid & 63;
  const int wr = w >> 1, wc = w & 1;
  const int lr = l & 15, lk = l >> 4;

  // XCD-aware swizzle (8192 % 8 == 0 -> simple form is bijective)
  int swz = (blockIdx.x & 7) * 1024 + (blockIdx.x >> 3);
  const int mt = swz >> 6, nt = swz & 63;
  const int m0 = mt * 128, n0 = nt * 128;

  if (PHASE == 2 && tid < 128) thr_s[tid] = thr[m0 + tid];

  f4v acc[4][4];
#pragma unroll
  for (int i = 0; i < 4; ++i)
#pragma unroll
    for (int j = 0; j < 4; ++j) acc[i][j] = (f4v){0.f, 0.f, 0.f, 0.f};

  for (int kt = 0; kt < 4; ++kt) {
    const int k0 = kt * 64;
    // stage A and B (linear LDS; global_load_lds width 16)
#pragma unroll
    for (int j = 0; j < 4; ++j) {
      int c = (j * 4 + w) * 64 + l;        // chunk 0..1023
      int row = c >> 3, c8 = c & 7;
      gld16(&As[c * 8], &xt[(size_t)(m0 + row) * C_ + k0 + c8 * 8]);
      gld16(&Bs[c * 8], &cbh[(size_t)(n0 + row) * C_ + k0 + c8 * 8]);
    }
    __syncthreads();   // drains vmcnt -> tiles ready
#pragma unroll
    for (int kk = 0; kk < 2; ++kk) {
      s8v a[4], b[4];
#pragma unroll
      for (int i = 0; i < 4; ++i) {
        int row = wr * 64 + i * 16 + lr;
        a[i] = *(const s8v*)&As[row * 64 + (kk * 4 + lk) * 8];
      }
#pragma unroll
      for (int j = 0; j < 4; ++j) {
        int row = wc * 64 + j * 16 + lr;
        b[j] = *(const s8v*)&Bs[row * 64 + (kk * 4 + lk) * 8];
      }
#pragma unroll
      for (int i = 0; i < 4; ++i)
#pragma unroll
        for (int j = 0; j < 4; ++j)
          acc[i][j] = __builtin_amdgcn_mfma_f32_16x16x32_bf16(a[i], b[j], acc[i][j], 0, 0, 0);
    }
    __syncthreads();   // readers done before next stage overwrites
  }

  // epilogue
  float cq[4], xq[4][4];
#pragma unroll
  for (int j = 0; j < 4; ++j) cq[j] = csq[n0 + wc * 64 + j * 16 + lr];
#pragma unroll
  for (int i = 0; i < 4; ++i)
#pragma unroll
    for (int r = 0; r < 4; ++r)
      xq[i][r] = xsq[m0 + wr * 64 + i * 16 + lk * 4 + r];

  if (PHASE == 1) {
    float rm[4][4];
#pragma unroll
    for (int i = 0; i < 4; ++i)
#pragma unroll
      for (int r = 0; r < 4; ++r) rm[i][r] = -1e30f;
#pragma unroll
    for (int i = 0; i < 4; ++i)
#pragma unroll
      for (int j = 0; j < 4; ++j)
#pragma unroll
        for (int r = 0; r < 4; ++r) {
          float d2 = __fsub_rn(__fadd_rn(xq[i][r], cq[j]),
                               __fmul_rn(2.0f, acc[i][j][r]));
          rm[i][r] = fmaxf(rm[i][r], d2);
        }
#pragma unroll
    for (int off = 1; off < 16; off <<= 1)
#pragma unroll
      for (int i = 0; i < 4; ++i)
#pragma unroll
        for (int r = 0; r < 4; ++r)
          rm[i][r] = fmaxf(rm[i][r], __shfl_xor(rm[i][r], off, 64));
    if (lr == 0) {
#pragma unroll
      for (int i = 0; i < 4; ++i)
#pragma unroll
        for (int r = 0; r < 4; ++r)
          red[wr * 64 + i * 16 + lk * 4 + r][wc] = rm[i][r];
    }
    __syncthreads();
    if (tid < 128)
      lmax[(size_t)(m0 + tid) * 64 + nt] = fmaxf(red[tid][0], red[tid][1]);
  } else {
#pragma unroll
    for (int i = 0; i < 4; ++i)
#pragma unroll
      for (int j = 0; j < 4; ++j)
#pragma unroll
        for (int r = 0; r < 4; ++r) {
          float d2 = __fsub_rn(__fadd_rn(xq[i][r], cq[j]),
                               __fmul_rn(2.0f, acc[i][j][r]));
          int row = wr * 64 + i * 16 + lk * 4 + r;
          if (d2 >= thr_s[row]) {
            u32 idx = atomicAdd(cnt, 1u);
            if (idx < LIST_CAP)
              list[idx] = ((u32)(m0 + row) << 13) | (u32)(n0 + wc * 64 + j * 16 + lr);
          }
        }
  }
}

// per-row global approx max -> rigorous threshold
__global__ void vq_thr(const float* __restrict__ lmax, const float* __restrict__ xsq,
                       const int* __restrict__ maxcs, float* __restrict__ thr) {
  int m = blockIdx.x * 256 + threadIdx.x;   // 64 blocks
  const float* p = &lmax[(size_t)m * 64];
  float g = -1e30f;
#pragma unroll
  for (int i = 0; i < 16; ++i) {
    float4 v = *(const float4*)&p[i * 4];
    g = fmaxf(g, fmaxf(fmaxf(v.x, v.y), fmaxf(v.z, v.w)));
  }
  float mc = __int_as_float(*maxcs);
  // |d2_approx - d2_exact| <= 2*((1+2^-8)^2-1)*sqrt(xsq*csq) + accum slack
  float marg = 0.0165f * sqrtf(xsq[m] * mc) + 0.15f;
  thr[m] = g - marg;
}

// exact fp32 rescore of candidates; one wave per candidate
__global__ void __launch_bounds__(256)
vq_rescore(const u32* __restrict__ list, const u32* __restrict__ cnt,
           const float* __restrict__ xtf, const float* __restrict__ cb,
           const float* __restrict__ xsq, const float* __restrict__ csq,
           u64* __restrict__ keys) {
  u32 n = *cnt; if (n > LIST_CAP) n = LIST_CAP;
  int wid = (blockIdx.x * 256 + threadIdx.x) >> 6;
  int l = threadIdx.x & 63;
  int nw = (gridDim.x * 256) >> 6;
  for (u32 c = wid; c < n; c += nw) {
    u32 e = list[c];
    int m = (int)(e >> 13), k = (int)(e & 8191u);
    float4 xv = *(const float4*)&xtf[(size_t)m * C_ + l * 4];
    float4 cv = *(const float4*)&cb[(size_t)k * C_ + l * 4];
    float p = xv.x * cv.x + xv.y * cv.y + xv.z * cv.z + xv.w * cv.w;
#pragma unroll
    for (int off = 1; off < 64; off <<= 1) p += __shfl_xor(p, off, 64);
    if (l == 0) {
      float d2 = __fsub_rn(__fadd_rn(xsq[m], csq[k]), __fmul_rn(2.0f, p));
      float dist = sqrtf(fmaxf(d2, 0.0f));
      u64 key = ((u64)__float_as_uint(dist) << 32) |
                (u64)(0xFFFFFFFFu - (u32)k);
      atomicMax(&keys[m], key);
    }
  }
}

// ---------------- round-1 fp32 fallback GEMM (used if ws too small) ----------------
#define TILE_M 128
#define TILE_N 256
#define KCH 32
#define NSPLIT 4
#define CODES_PER_SPLIT (K_ / NSPLIT)
#define NTILES (CODES_PER_SPLIT / TILE_N)

__global__ void __launch_bounds__(256, 2)
vq_dist_argmax(const float* __restrict__ x, const float* __restrict__ cb,
               const float* __restrict__ xsq, const float* __restrict__ csq,
               u64* __restrict__ keys) {
  __shared__ float As[KCH * TILE_M];
  __shared__ float Bs[TILE_N * KCH];
  const int tid = threadIdx.x;
  const int bid = blockIdx.x;
  const int mtile = bid & 127;
  const int split = bid >> 7;
  const int bb = mtile >> 4;
  const int l0 = (mtile & 15) * TILE_M;
  const int m0 = mtile * TILE_M;
  const int tr = tid & 15;
  const int tc = tid >> 4;
  float xq[8];
#pragma unroll
  for (int jr = 0; jr < 2; ++jr)
#pragma unroll
    for (int i = 0; i < 4; ++i)
      xq[jr * 4 + i] = xsq[m0 + 4 * tr + 64 * jr + i];
  float bestv[8]; int bestk[8];
#pragma unroll
  for (int r = 0; r < 8; ++r) { bestv[r] = -1.0f; bestk[r] = 0; }
  for (int ntb = 0; ntb < NTILES; ++ntb) {
    const int k0 = split * CODES_PER_SPLIT + ntb * TILE_N;
    float accf[16][8];
#pragma unroll
    for (int jc = 0; jc < 16; ++jc)
#pragma unroll
      for (int r = 0; r < 8; ++r) accf[jc][r] = 0.0f;
    for (int ccc = 0; ccc < C_ / KCH; ++ccc) {
      const int c0 = ccc * KCH;
      __syncthreads();
#pragma unroll
      for (int j = 0; j < 4; ++j) {
        int idx = tid + 256 * j;
        int c = idx >> 5, qm = idx & 31;
        float4 v = *(const float4*)&x[(size_t)(bb * C_ + c0 + c) * L_ + l0 + 4 * qm];
        *(float4*)&As[c * TILE_M + 4 * qm] = v;
      }
#pragma unroll
      for (int it = 0; it < 8; ++it) {
        int k = (tid >> 3) + 32 * it;
        int c4 = tid & 7;
        float4 v = *(const float4*)&cb[(size_t)(k0 + k) * C_ + c0 + 4 * c4];
        *(float4*)&Bs[32 * k + 4 * (c4 ^ (k & 7))] = v;
      }
      __syncthreads();
#pragma unroll 2
      for (int c4 = 0; c4 < 8; ++c4) {
        float a_[4][8];
#pragma unroll
        for (int ci = 0; ci < 4; ++ci) {
          int c = 4 * c4 + ci;
          float4 t0 = *(const float4*)&As[c * TILE_M + 4 * tr];
          float4 t1 = *(const float4*)&As[c * TILE_M + 4 * tr + 64];
          a_[ci][0] = t0.x; a_[ci][1] = t0.y; a_[ci][2] = t0.z; a_[ci][3] = t0.w;
          a_[ci][4] = t1.x; a_[ci][5] = t1.y; a_[ci][6] = t1.z; a_[ci][7] = t1.w;
        }
#pragma unroll
        for (int jc = 0; jc < 16; ++jc) {
          int k = tc + 16 * jc;
          float4 bv = *(const float4*)&Bs[32 * k + 4 * (c4 ^ (k & 7))];
          float bs[4] = {bv.x, bv.y, bv.z, bv.w};
#pragma unroll
          for (int ci = 0; ci < 4; ++ci)
#pragma unroll
            for (int r = 0; r < 8; ++r)
              accf[jc][r] = fmaf(a_[ci][r], bs[ci], accf[jc][r]);
        }
      }
    }
#pragma unroll
    for (int jc = 0; jc < 16; ++jc) {
      int kg = k0 + tc + 16 * jc;
      float cs = csq[kg];
#pragma unroll
      for (int r = 0; r < 8; ++r) {
        float d2 = __fsub_rn(__fadd_rn(xq[r], cs), __fmul_rn(2.0f, accf[jc][r]));
        float dist = sqrtf(fmaxf(d2, 0.0f));
        if (dist > bestv[r]) { bestv[r] = dist; bestk[r] = kg; }
      }
    }
  }
#pragma unroll
  for (int r = 0; r < 8; ++r) {
    int m = m0 + 4 * tr + 64 * (r >> 2) + (r & 3);
    u64 key = ((u64)__float_as_uint(bestv[r]) << 32) |
              (u64)(0xFFFFFFFFu - (u32)bestk[r]);
    atomicMax(&keys[m], key);
  }
}

// ---------------- outputs ----------------

__global__ void vq_code(const u64* __restrict__ keys, float* __restrict__ out) {
  int m = blockIdx.x * 256 + threadIdx.x;
  u32 k = 0xFFFFFFFFu - (u32)(keys[m] & 0xFFFFFFFFull);
  out[m] = (float)k;
}

__global__ void __launch_bounds__(256)
vq_gather(const u64* __restrict__ keys, const float* __restrict__ cb,
          const float* __restrict__ x, float* __restrict__ emb,
          float* __restrict__ loss_acc) {
  __shared__ float rows[32 * 260];
  __shared__ int codes_s[32];
  __shared__ float partial[4];
  int t = threadIdx.x;
  int b = blockIdx.x >> 6;
  int l0 = (blockIdx.x & 63) * 32;
  if (t < 32) {
    u64 key = keys[b * L_ + l0 + t];
    codes_s[t] = (int)(0xFFFFFFFFu - (u32)(key & 0xFFFFFFFFull));
  }
  __syncthreads();
  {
    int r = t >> 3, c4 = t & 7;
    const float* src = cb + (size_t)codes_s[r] * C_;
#pragma unroll
    for (int j = 0; j < 8; ++j) {
      float4 v = *(const float4*)&src[(c4 + 8 * j) * 4];
      *(float4*)&rows[r * 260 + (c4 + 8 * j) * 4] = v;
    }
  }
  __syncthreads();
  float ls = 0.0f;
  int l = t & 31, cg = t >> 5;
#pragma unroll 4
  for (int cs = 0; cs < 32; ++cs) {
    int c = cg * 32 + cs;
    float v = rows[l * 260 + c];
    size_t gi = (size_t)(b * C_ + c) * L_ + l0 + l;
    emb[gi] = v;
    float d = x[gi] - v;
    ls = fmaf(d, d, ls);
  }
#pragma unroll
  for (int off = 1; off < 64; off <<= 1) ls += __shfl_xor(ls, off, 64);
  if ((t & 63) == 0) partial[t >> 6] = ls;
  __syncthreads();
  if (t == 0)
    atomicAdd(loss_acc, partial[0] + partial[1] + partial[2] + partial[3]);
}

__global__ void vq_loss(const float* __restrict__ loss_acc, float* __restrict__ out) {
  out[0] = loss_acc[0] / 4194304.0f;
}

extern "C" void kernel_launch(void* const* d_in, const int* in_sizes, int n_in,
                              void* d_out, int out_size, void* d_ws, size_t ws_size,
                              hipStream_t stream) {
  const float* x  = (const float*)d_in[0];
  const float* cb = (const float*)d_in[1];
  float* out = (float*)d_out;             // [code(16384) | emb(4194304) | loss(1)]
  char* ws = (char*)d_ws;

  u64* keys      = (u64*)(ws + WS_KEYS);
  u32* cnt       = (u32*)(ws + WS_CNT);
  int* maxcs     = (int*)(ws + WS_MAXCS);
  float* loss_a  = (float*)(ws + WS_LOSS);
  float* xsq     = (float*)(ws + WS_XSQ);
  float* csq     = (float*)(ws + WS_CSQ);
  float* thr     = (float*)(ws + WS_THR);
  float* lmax    = (float*)(ws + WS_LMAX);
  u32* list      = (u32*)(ws + WS_LIST);
  ushort_t* xth  = (ushort_t*)(ws + WS_XTH);
  ushort_t* cbh  = (ushort_t*)(ws + WS_CBH);
  float* xtf     = out + M_;              // emb region doubles as fp32 x^T scratch

  hipMemsetAsync(ws, 0, 131084, stream);  // keys + cnt + maxcs + loss

  if (ws_size >= (size_t)WS_NEED) {
    vq_transpose<<<1024, 256, 0, stream>>>(x, xtf, xth);
    vq_xsq<<<M_ / 256, 256, 0, stream>>>(x, xsq);
    vq_csq<<<K_ / 16, 256, 0, stream>>>(cb, csq, maxcs);
    vq_cbconv<<<2048, 256, 0, stream>>>(cb, cbh);
    vq_mfma_pass<1><<<8192, 256, 0, stream>>>(xth, cbh, xsq, csq, lmax, nullptr, nullptr, nullptr);
    vq_thr<<<M_ / 256, 256, 0, stream>>>(lmax, xsq, maxcs, thr);
    vq_mfma_pass<2><<<8192, 256, 0, stream>>>(xth, cbh, xsq, csq, nullptr, thr, list, cnt);
    vq_rescore<<<256, 256, 0, stream>>>(list, cnt, xtf, cb, xsq, csq, keys);
  } else {
    vq_xsq<<<M_ / 256, 256, 0, stream>>>(x, xsq);
    vq_csq<<<K_ / 16, 256, 0, stream>>>(cb, csq, maxcs);
    vq_dist_argmax<<<128 * NSPLIT, 256, 0, stream>>>(x, cb, xsq, csq, keys);
  }

  vq_code<<<M_ / 256, 256, 0, stream>>>(keys, out);
  vq_gather<<<(B_ * L_) / 32, 256, 0, stream>>>(keys, cb, x, out + M_, loss_a);
  vq_loss<<<1, 1, 0, stream>>>(loss_a, out + M_ + (size_t)B_ * C_ * L_);
}